// Round 1
// baseline (710.539 us; speedup 1.0000x reference)
//
#include <hip/hip_runtime.h>
#include <math.h>

// Problem constants
#define B_N 32768
#define L_N 128
#define M_N 1024
#define TB 64        // rows of u per block
#define TM 64        // centres per m-tile
#define NTHREADS 256

// ws layout (floats): [0,1024): c_sq ; [1024,2048): inv_sig2 ; [2048,2048+B_N): g

__global__ void lebnn_precompute(const float* __restrict__ centres,
                                 const float* __restrict__ log_sigmas,
                                 float* __restrict__ c_sq,
                                 float* __restrict__ inv_sig2) {
    int m = blockIdx.x * blockDim.x + threadIdx.x;
    if (m >= M_N) return;
    const float4* row = (const float4*)(centres + (size_t)m * L_N);
    float s = 0.f;
#pragma unroll
    for (int i = 0; i < L_N / 4; ++i) {
        float4 v = row[i];
        s += v.x * v.x + v.y * v.y + v.z * v.z + v.w * v.w;
    }
    c_sq[m] = s;
    inv_sig2[m] = expf(-2.f * log_sigmas[m]);
}

// ---------------- Pass 1: s[b] = sum_m w_m * phi(b,m)  ->  g[b] = elu'(s) ----
__global__ __launch_bounds__(NTHREADS) void lebnn_pass1(
    const float* __restrict__ u, const float* __restrict__ centres,
    const float* __restrict__ lin_w, const float* __restrict__ c_sq,
    const float* __restrict__ inv_sig2, float* __restrict__ g_out)
{
    extern __shared__ float smem[];
    float* u_t  = smem;              // [128][64]  transposed u tile
    float* c2   = u_t + 128 * TB;    // [64][132]  centres tile (padded)
    float* sred = c2 + TM * 132;     // [16][68]
    float* usq  = sred + 16 * 68;    // [64]

    const int tid = threadIdx.x;
    const int tx = tid & 15;         // b-group (4 rows)
    const int ty = tid >> 4;         // m-group (4 centres)
    const int b0 = blockIdx.x * TB;

    // stage u transposed: u_t[l][b]
#pragma unroll
    for (int it = 0; it < 8; ++it) {
        int idx = it * NTHREADS + tid;
        int row = idx >> 5;          // 0..63
        int lq  = idx & 31;          // 0..31
        float4 v = *(const float4*)(u + (size_t)(b0 + row) * L_N + lq * 4);
        u_t[(lq * 4 + 0) * TB + row] = v.x;
        u_t[(lq * 4 + 1) * TB + row] = v.y;
        u_t[(lq * 4 + 2) * TB + row] = v.z;
        u_t[(lq * 4 + 3) * TB + row] = v.w;
    }
    __syncthreads();
    if (tid < TB) {
        float s = 0.f;
        for (int k = 0; k < L_N; ++k) { float x = u_t[k * TB + tid]; s += x * x; }
        usq[tid] = s;
    }
    __syncthreads();

    float usq_r[4];
#pragma unroll
    for (int i = 0; i < 4; ++i) usq_r[i] = usq[tx * 4 + i];

    float partial[4] = {0.f, 0.f, 0.f, 0.f};

    for (int mt = 0; mt < M_N / TM; ++mt) {
        int m0 = mt * TM;
        // stage centres tile [m][l] with +4 pad
#pragma unroll
        for (int it = 0; it < 8; ++it) {
            int idx = it * NTHREADS + tid;
            int mr = idx >> 5, lq = idx & 31;
            float4 v = *(const float4*)(centres + (size_t)(m0 + mr) * L_N + lq * 4);
            *(float4*)&c2[mr * 132 + lq * 4] = v;
        }
        __syncthreads();

        float acc[4][4] = {};
        for (int k = 0; k < L_N; ++k) {
            float4 uu = *(const float4*)&u_t[k * TB + tx * 4];
            float ua[4] = {uu.x, uu.y, uu.z, uu.w};
#pragma unroll
            for (int j = 0; j < 4; ++j) {
                float cc = c2[(ty * 4 + j) * 132 + k];
#pragma unroll
                for (int i = 0; i < 4; ++i) acc[i][j] = fmaf(ua[i], cc, acc[i][j]);
            }
        }
        __syncthreads();

#pragma unroll
        for (int j = 0; j < 4; ++j) {
            int m = m0 + ty * 4 + j;
            float csq = c_sq[m], is2 = inv_sig2[m], w = lin_w[m];
#pragma unroll
            for (int i = 0; i < 4; ++i) {
                float raw = usq_r[i] + csq - 2.f * acc[i][j];
                float sq  = fmaxf(raw, 0.f);
                float phi = sqrtf(fmaf(sq, is2, 1.f));
                partial[i] = fmaf(w, phi, partial[i]);
            }
        }
    }

#pragma unroll
    for (int i = 0; i < 4; ++i) sred[ty * 68 + tx * 4 + i] = partial[i];
    __syncthreads();
    if (tid < TB) {
        float s = 0.f;
#pragma unroll
        for (int t = 0; t < 16; ++t) s += sred[t * 68 + tid];
        g_out[b0 + tid] = (s > 0.f) ? 1.f : expf(s);
    }
}

// ---------------- Pass 2: out = u*(1 + sum coeff) - coeff @ centres ----------
__global__ __launch_bounds__(NTHREADS) void lebnn_pass2(
    const float* __restrict__ u, const float* __restrict__ centres,
    const float* __restrict__ lin_w, const float* __restrict__ c_sq,
    const float* __restrict__ inv_sig2, const float* __restrict__ g_in,
    float* __restrict__ out)
{
    extern __shared__ float smem[];
    float* u_t  = smem;              // [128][64]
    float* c2   = u_t + 128 * TB;    // [64][132]
    float* cfl  = c2 + TM * 132;     // coeff [64 m][64 b]
    float* rred = cfl + TM * TB;     // [16][68]
    float* usq  = rred + 16 * 68;    // [64]
    float* gsh  = usq + TB;          // [64]
    float* rtot = gsh + TB;          // [64]

    const int tid = threadIdx.x;
    const int tx = tid & 15;         // b-group of 4  (GEMM1 + GEMM2)
    const int ty = tid >> 4;         // m-group of 4 (GEMM1) / l-group of 8 (GEMM2)
    const int b0 = blockIdx.x * TB;

#pragma unroll
    for (int it = 0; it < 8; ++it) {
        int idx = it * NTHREADS + tid;
        int row = idx >> 5;
        int lq  = idx & 31;
        float4 v = *(const float4*)(u + (size_t)(b0 + row) * L_N + lq * 4);
        u_t[(lq * 4 + 0) * TB + row] = v.x;
        u_t[(lq * 4 + 1) * TB + row] = v.y;
        u_t[(lq * 4 + 2) * TB + row] = v.z;
        u_t[(lq * 4 + 3) * TB + row] = v.w;
    }
    __syncthreads();
    if (tid < TB) {
        float s = 0.f;
        for (int k = 0; k < L_N; ++k) { float x = u_t[k * TB + tid]; s += x * x; }
        usq[tid] = s;
        gsh[tid] = g_in[b0 + tid];
    }
    __syncthreads();

    float usq_r[4], g_r[4];
#pragma unroll
    for (int i = 0; i < 4; ++i) { usq_r[i] = usq[tx * 4 + i]; g_r[i] = gsh[tx * 4 + i]; }

    float T[4][8] = {};              // out accumulator: b = tx*4+i, l = ty*8+j
    float rowAcc[4] = {0.f, 0.f, 0.f, 0.f};

    for (int mt = 0; mt < M_N / TM; ++mt) {
        int m0 = mt * TM;
#pragma unroll
        for (int it = 0; it < 8; ++it) {
            int idx = it * NTHREADS + tid;
            int mr = idx >> 5, lq = idx & 31;
            float4 v = *(const float4*)(centres + (size_t)(m0 + mr) * L_N + lq * 4);
            *(float4*)&c2[mr * 132 + lq * 4] = v;
        }
        __syncthreads();

        float acc[4][4] = {};
        for (int k = 0; k < L_N; ++k) {
            float4 uu = *(const float4*)&u_t[k * TB + tx * 4];
            float ua[4] = {uu.x, uu.y, uu.z, uu.w};
#pragma unroll
            for (int j = 0; j < 4; ++j) {
                float cc = c2[(ty * 4 + j) * 132 + k];
#pragma unroll
                for (int i = 0; i < 4; ++i) acc[i][j] = fmaf(ua[i], cc, acc[i][j]);
            }
        }

        // coeff = g * w * is2 / phi  (gated), scattered to cfl[m][b]
#pragma unroll
        for (int j = 0; j < 4; ++j) {
            int m = m0 + ty * 4 + j;
            float csq = c_sq[m], is2 = inv_sig2[m], w = lin_w[m];
#pragma unroll
            for (int i = 0; i < 4; ++i) {
                float raw = usq_r[i] + csq - 2.f * acc[i][j];
                float co = 0.f;
                if (raw > 0.f) {
                    float phi_inv = rsqrtf(fmaf(raw, is2, 1.f));
                    co = g_r[i] * w * is2 * phi_inv;
                }
                rowAcc[i] += co;
                cfl[(ty * 4 + j) * TB + tx * 4 + i] = co;
            }
        }
        __syncthreads();

        // GEMM-2: T[b][l] += coeff[b][m] * centres[m][l]
        for (int mm = 0; mm < TM; ++mm) {
            float4 cf = *(const float4*)&cfl[mm * TB + tx * 4];
            float cfa[4] = {cf.x, cf.y, cf.z, cf.w};
            float4 a0 = *(const float4*)&c2[mm * 132 + ty * 8];
            float4 a1 = *(const float4*)&c2[mm * 132 + ty * 8 + 4];
            float cv[8] = {a0.x, a0.y, a0.z, a0.w, a1.x, a1.y, a1.z, a1.w};
#pragma unroll
            for (int i = 0; i < 4; ++i)
#pragma unroll
                for (int j = 0; j < 8; ++j) T[i][j] = fmaf(cfa[i], cv[j], T[i][j]);
        }
        __syncthreads();
    }

    // reduce rowAcc over ty
#pragma unroll
    for (int i = 0; i < 4; ++i) rred[ty * 68 + tx * 4 + i] = rowAcc[i];
    __syncthreads();
    if (tid < TB) {
        float s = 0.f;
#pragma unroll
        for (int t = 0; t < 16; ++t) s += rred[t * 68 + tid];
        rtot[tid] = s;
    }
    __syncthreads();

#pragma unroll
    for (int i = 0; i < 4; ++i) {
        int b = tx * 4 + i;
        float scale = 1.f + rtot[b];
        float4 o0, o1;
        o0.x = u_t[(ty * 8 + 0) * TB + b] * scale - T[i][0];
        o0.y = u_t[(ty * 8 + 1) * TB + b] * scale - T[i][1];
        o0.z = u_t[(ty * 8 + 2) * TB + b] * scale - T[i][2];
        o0.w = u_t[(ty * 8 + 3) * TB + b] * scale - T[i][3];
        o1.x = u_t[(ty * 8 + 4) * TB + b] * scale - T[i][4];
        o1.y = u_t[(ty * 8 + 5) * TB + b] * scale - T[i][5];
        o1.z = u_t[(ty * 8 + 6) * TB + b] * scale - T[i][6];
        o1.w = u_t[(ty * 8 + 7) * TB + b] * scale - T[i][7];
        *(float4*)(out + (size_t)(b0 + b) * L_N + ty * 8)     = o0;
        *(float4*)(out + (size_t)(b0 + b) * L_N + ty * 8 + 4) = o1;
    }
}

extern "C" void kernel_launch(void* const* d_in, const int* in_sizes, int n_in,
                              void* d_out, int out_size, void* d_ws, size_t ws_size,
                              hipStream_t stream) {
    const float* u          = (const float*)d_in[0];
    const float* centres    = (const float*)d_in[1];
    const float* log_sigmas = (const float*)d_in[2];
    const float* lin_w      = (const float*)d_in[3];
    float* out = (float*)d_out;
    float* ws  = (float*)d_ws;

    float* c_sq = ws;
    float* is2  = ws + 1024;
    float* g    = ws + 2048;

    lebnn_precompute<<<(M_N + 255) / 256, 256, 0, stream>>>(centres, log_sigmas, c_sq, is2);

    size_t smem1 = (size_t)(128 * TB + TM * 132 + 16 * 68 + TB) * sizeof(float);
    size_t smem2 = (size_t)(128 * TB + TM * 132 + TM * TB + 16 * 68 + 3 * TB) * sizeof(float);
    hipFuncSetAttribute((const void*)lebnn_pass1, hipFuncAttributeMaxDynamicSharedMemorySize, (int)smem1);
    hipFuncSetAttribute((const void*)lebnn_pass2, hipFuncAttributeMaxDynamicSharedMemorySize, (int)smem2);

    lebnn_pass1<<<B_N / TB, NTHREADS, smem1, stream>>>(u, centres, lin_w, c_sq, is2, g);
    lebnn_pass2<<<B_N / TB, NTHREADS, smem2, stream>>>(u, centres, lin_w, c_sq, is2, g, out);
}

// Round 3
// 152.279 us; speedup vs baseline: 4.6660x; 4.6660x over previous
//
#include <hip/hip_runtime.h>
#include <math.h>

#define B_N 32768
#define L_N 128
#define M_N 1024
#define NT 512
#define TB 64
#define TM 64
#define NCHUNK (M_N / TM)

typedef __bf16 v8bf __attribute__((ext_vector_type(8)));
typedef __bf16 v4bf __attribute__((ext_vector_type(4)));
typedef float  v4f  __attribute__((ext_vector_type(4)));

#define MFMA(a, b, c) __builtin_amdgcn_mfma_f32_16x16x32_bf16(a, b, c, 0, 0, 0)

// element strides
#define US  136   // u_bf [64][136] bf16
#define CNS 136   // c_n  [64][136] bf16
#define CFS 68    // cfl  [64 m][68 b] fp32

// byte offsets into dynamic LDS
#define OFF_UBF   0
#define OFF_CN    17408
#define OFF_CFL   34816
#define OFF_USQ   52224
#define OFF_UPART 52480
#define OFF_SRED  54784
#define OFF_RRED  55936
#define OFF_G     57088
#define OFF_RS    57344
#define SMEM_BYTES 57600

__device__ inline v8bf pack8(float4 a, float4 b) {
    v8bf v;
    v[0] = (__bf16)a.x; v[1] = (__bf16)a.y; v[2] = (__bf16)a.z; v[3] = (__bf16)a.w;
    v[4] = (__bf16)b.x; v[5] = (__bf16)b.y; v[6] = (__bf16)b.z; v[7] = (__bf16)b.w;
    return v;
}

__global__ void lebnn_precompute(const float* __restrict__ centres,
                                 const float* __restrict__ log_sigmas,
                                 const float* __restrict__ lin_w,
                                 float4* __restrict__ cpack) {
    int m = blockIdx.x * blockDim.x + threadIdx.x;
    if (m >= M_N) return;
    const float4* row = (const float4*)(centres + (size_t)m * L_N);
    float s = 0.f;
#pragma unroll
    for (int i = 0; i < L_N / 4; ++i) {
        float4 v = row[i];
        s += v.x * v.x + v.y * v.y + v.z * v.z + v.w * v.w;
    }
    float4 p;
    p.x = s;
    p.y = expf(-2.f * log_sigmas[m]);   // 1/sigma^2
    p.z = lin_w[m];
    p.w = 0.f;
    cpack[m] = p;
}

__global__ __launch_bounds__(NT) void lebnn_fused(
    const float* __restrict__ u, const float* __restrict__ centres,
    const float4* __restrict__ cpack, float* __restrict__ out)
{
    extern __shared__ char smem[];
    __bf16* u_bf = (__bf16*)(smem + OFF_UBF);
    __bf16* c_n  = (__bf16*)(smem + OFF_CN);
    float*  cfl  = (float*)(smem + OFF_CFL);
    float* usq_s = (float*)(smem + OFF_USQ);
    float* upart = (float*)(smem + OFF_UPART);
    float* sred  = (float*)(smem + OFF_SRED);
    float* rred  = (float*)(smem + OFF_RRED);
    float* gsh   = (float*)(smem + OFF_G);
    float* rssh  = (float*)(smem + OFF_RS);

    const int tid  = threadIdx.x;
    const int w    = tid >> 6;
    const int lane = tid & 63;
    const int l15  = lane & 15;
    const int l4   = lane >> 4;
    const int bh   = w >> 2;        // GEMM1 b-half
    const int mq   = w & 3;         // GEMM1 m-quarter
    const int tx   = tid & 15;      // GEMM2/epilogue: b-group of 4
    const int ty   = tid >> 4;      // GEMM2/epilogue: l-group of 4 (0..31)
    const int b0   = blockIdx.x * TB;

    // ---------------- stage u (fp32 -> bf16) + row sumsq ----------------
    {
        int row = tid >> 3, seg = tid & 7;
        const float* up = u + (size_t)(b0 + row) * L_N + seg * 16;
        float4 a0 = *(const float4*)(up);
        float4 a1 = *(const float4*)(up + 4);
        float4 a2 = *(const float4*)(up + 8);
        float4 a3 = *(const float4*)(up + 12);
        float ps = a0.x*a0.x + a0.y*a0.y + a0.z*a0.z + a0.w*a0.w
                 + a1.x*a1.x + a1.y*a1.y + a1.z*a1.z + a1.w*a1.w
                 + a2.x*a2.x + a2.y*a2.y + a2.z*a2.z + a2.w*a2.w
                 + a3.x*a3.x + a3.y*a3.y + a3.z*a3.z + a3.w*a3.w;
        *(v8bf*)&u_bf[row * US + seg * 16]     = pack8(a0, a1);
        *(v8bf*)&u_bf[row * US + seg * 16 + 8] = pack8(a2, a3);
        upart[row * 9 + seg] = ps;
    }
    __syncthreads();
    if (tid < TB) {
        float s = 0.f;
#pragma unroll
        for (int i = 0; i < 8; ++i) s += upart[tid * 9 + i];
        usq_s[tid] = s;
    }
    __syncthreads();

    // ---------------- preload u fragments + usq regs ----------------
    v8bf uf[2][4];
#pragma unroll
    for (int bt = 0; bt < 2; ++bt)
#pragma unroll
        for (int kk = 0; kk < 4; ++kk)
            uf[bt][kk] = *(v8bf*)&u_bf[(bh*32 + bt*16 + l15) * US + kk*32 + l4*8];

    float usq_r[2][4];
#pragma unroll
    for (int bt = 0; bt < 2; ++bt)
#pragma unroll
        for (int r = 0; r < 4; ++r)
            usq_r[bt][r] = usq_s[bh*32 + bt*16 + l4*4 + r];

    float s_p[2][4] = {{0.f,0.f,0.f,0.f},{0.f,0.f,0.f,0.f}};
    float r_p[2][4] = {{0.f,0.f,0.f,0.f},{0.f,0.f,0.f,0.f}};
    float T[4][4] = {{0.f}};

    const int rp = tid >> 4;   // staging row-pair 0..31
    const int cg = tid & 15;   // staging col-group

    // ---------------- main loop over m-chunks ----------------
    for (int mt = 0; mt < NCHUNK; ++mt) {
        const int m0 = mt * TM;
        __syncthreads();   // A: prev GEMM2 reads done before restaging
        {
            const float* cp0 = centres + (size_t)(m0 + 2*rp) * L_N + cg * 8;
            float4 r0a = *(const float4*)(cp0);
            float4 r0b = *(const float4*)(cp0 + 4);
            float4 r1a = *(const float4*)(cp0 + L_N);
            float4 r1b = *(const float4*)(cp0 + L_N + 4);
            *(v8bf*)&c_n[(2*rp)     * CNS + cg*8] = pack8(r0a, r0b);
            *(v8bf*)&c_n[(2*rp + 1) * CNS + cg*8] = pack8(r1a, r1b);
        }
        float4 cpv = cpack[m0 + mq*16 + l15];
        __syncthreads();   // B: tiles staged

        // GEMM1: dots[b][m] for this wave's [32b][16m]
        v4f dot[2];
        dot[0] = (v4f){0.f,0.f,0.f,0.f};
        dot[1] = (v4f){0.f,0.f,0.f,0.f};
#pragma unroll
        for (int kk = 0; kk < 4; ++kk) {
            v8bf bfr = *(v8bf*)&c_n[(mq*16 + l15) * CNS + kk*32 + l4*8];
            dot[0] = MFMA(uf[0][kk], bfr, dot[0]);
            dot[1] = MFMA(uf[1][kk], bfr, dot[1]);
        }

        // elementwise: q = w*is2*gate/phi ; s += w*phi ; q -> cfl[m][b] fp32
#pragma unroll
        for (int bt = 0; bt < 2; ++bt) {
#pragma unroll
            for (int r = 0; r < 4; ++r) {
                float dv  = dot[bt][r];
                float raw = fmaf(-2.f, dv, usq_r[bt][r] + cpv.x);
                float x   = fmaf(fmaxf(raw, 0.f), cpv.y, 1.f);
                float ri  = rsqrtf(x);
                s_p[bt][r] = fmaf(cpv.z, x * ri, s_p[bt][r]);
                float qv  = (raw > 0.f) ? cpv.z * cpv.y * ri : 0.f;
                r_p[bt][r] += qv;
                cfl[(mq*16 + l15) * CFS + bh*32 + bt*16 + l4*4 + r] = qv;
            }
        }
        __syncthreads();   // C: cfl ready

        // GEMM2 (fp32 VALU, round-1-verified pattern):
        // T[b][l] += q[b][m] * C[m][l]
        for (int mm = 0; mm < TM; ++mm) {
            v4f cf = *(v4f*)&cfl[mm * CFS + tx*4];
            v4bf cb = *(v4bf*)&c_n[mm * CNS + ty*4];
            float cv[4] = {(float)cb[0], (float)cb[1], (float)cb[2], (float)cb[3]};
#pragma unroll
            for (int i = 0; i < 4; ++i)
#pragma unroll
                for (int j = 0; j < 4; ++j)
                    T[i][j] = fmaf(cf[i], cv[j], T[i][j]);
        }
    }

    __syncthreads();   // D

    // ---------------- reduce s, R over the 16-lane m-groups ----------------
#pragma unroll
    for (int bt = 0; bt < 2; ++bt)
#pragma unroll
        for (int r = 0; r < 4; ++r) {
#pragma unroll
            for (int msk = 1; msk < 16; msk <<= 1) {
                s_p[bt][r] += __shfl_xor(s_p[bt][r], msk, 64);
                r_p[bt][r] += __shfl_xor(r_p[bt][r], msk, 64);
            }
        }
    if (l15 == 0) {
#pragma unroll
        for (int bt = 0; bt < 2; ++bt)
#pragma unroll
            for (int r = 0; r < 4; ++r) {
                sred[w*36 + bt*16 + l4*4 + r] = s_p[bt][r];
                rred[w*36 + bt*16 + l4*4 + r] = r_p[bt][r];
            }
    }
    __syncthreads();   // E

    if (tid < TB) {
        int bhh = tid >> 5, rowr = tid & 31;
        float s = 0.f, R = 0.f;
#pragma unroll
        for (int i = 0; i < 4; ++i) {
            s += sred[(bhh*4 + i)*36 + rowr];
            R += rred[(bhh*4 + i)*36 + rowr];
        }
        float g = (s > 0.f) ? 1.f : expf(s);
        gsh[tid]  = g;
        rssh[tid] = fmaf(g, R, 1.f);
    }
    __syncthreads();   // F

    // ---------------- epilogue: per-thread 4b x 4l block ----------------
#pragma unroll
    for (int i = 0; i < 4; ++i) {
        int b = tx*4 + i;
        float rv = rssh[b];
        float gv = gsh[b];
        size_t idx = (size_t)(b0 + b) * L_N + ty*4;
        float4 uu = *(const float4*)(u + idx);
        float4 o;
        o.x = fmaf(uu.x, rv, -gv * T[i][0]);
        o.y = fmaf(uu.y, rv, -gv * T[i][1]);
        o.z = fmaf(uu.z, rv, -gv * T[i][2]);
        o.w = fmaf(uu.w, rv, -gv * T[i][3]);
        *(float4*)(out + idx) = o;
    }
}

extern "C" void kernel_launch(void* const* d_in, const int* in_sizes, int n_in,
                              void* d_out, int out_size, void* d_ws, size_t ws_size,
                              hipStream_t stream) {
    const float* u          = (const float*)d_in[0];
    const float* centres    = (const float*)d_in[1];
    const float* log_sigmas = (const float*)d_in[2];
    const float* lin_w      = (const float*)d_in[3];
    float* out = (float*)d_out;
    float4* cpack = (float4*)d_ws;   // 1024 * 16 B

    lebnn_precompute<<<(M_N + 255) / 256, 256, 0, stream>>>(centres, log_sigmas, lin_w, cpack);

    hipFuncSetAttribute((const void*)lebnn_fused,
                        hipFuncAttributeMaxDynamicSharedMemorySize, SMEM_BYTES);
    lebnn_fused<<<B_N / TB, NT, SMEM_BYTES, stream>>>(u, centres, cpack, out);
}